// Round 2
// baseline (42.483 us; speedup 1.0000x reference)
//
#include <hip/hip_runtime.h>
#include <math.h>

#define BB 16
#define NN 64
#define CC 256

typedef __attribute__((ext_vector_type(4))) float f32x4;

__device__ __forceinline__ float gelu_exact(float x) {
    return 0.5f * x * (1.0f + erff(x * 0.70710678118654752440f));
}

// K1: per-element MLP -> etpp; s = tmp+p1+p2 -> Spos/Sneg (one wave per row); out0 = img copy
__global__ void k1_mlp_reduce(const float* __restrict__ img,
                              const float* __restrict__ tmp,
                              const float* __restrict__ p1,
                              const float* __restrict__ p2,
                              const float* __restrict__ w1,
                              const float* __restrict__ b1,
                              const float* __restrict__ w2,
                              const float* __restrict__ b2,
                              float* __restrict__ etpp,
                              float* __restrict__ Spos,
                              float* __restrict__ Sneg,
                              float* __restrict__ out0) {
    int t    = threadIdx.x;
    int bn   = blockIdx.x * 4 + (t >> 6);   // one wave per (b,n) row
    int lane = t & 63;
    int base = bn * CC + lane * 4;

    f32x4 tv = *(const f32x4*)(tmp + base);
    f32x4 q1 = *(const f32x4*)(p1 + base);
    f32x4 q2 = *(const f32x4*)(p2 + base);
    f32x4 gv = *(const f32x4*)(img + base);
    *(f32x4*)(out0 + base) = gv;

    float bb2 = b2[0];
    f32x4 e;
    float sp = 0.0f, sn = 0.0f;
    #pragma unroll
    for (int u = 0; u < 4; ++u) {
        float acc = bb2;
        #pragma unroll
        for (int j = 0; j < 12; ++j) {
            float h = tv[u] * w1[j] + q1[u] * w1[12 + j] + q2[u] * w1[24 + j] + b1[j];
            acc += gelu_exact(h) * w2[j];
        }
        e[u] = acc;
        float s  = tv[u] + q1[u] + q2[u];
        float s2 = s * s;
        if (s >= 0.0f) sp += s2; else sn += s2;
    }
    *(f32x4*)(etpp + base) = e;

    #pragma unroll
    for (int off = 32; off > 0; off >>= 1) {
        sp += __shfl_down(sp, off);
        sn += __shfl_down(sn, off);
    }
    if (lane == 0) { Spos[bn] = sp; Sneg[bn] = sn; }
}

// K2: M[b,c,x] = sum_n etpp[b,n,c] * img[b,n,x]; 64x64 tile/block, 4x4 per thread
__global__ void k2_gemm_M(const float* __restrict__ etpp,
                          const float* __restrict__ img,
                          float* __restrict__ M) {
    __shared__ float es[64][68];
    __shared__ float is_[64][68];
    int b  = blockIdx.z;
    int c0 = blockIdx.y * 64;
    int x0 = blockIdx.x * 64;
    int t  = threadIdx.x;
    const float* eb = etpp + b * NN * CC;
    const float* ib = img  + b * NN * CC;

    #pragma unroll
    for (int k = 0; k < 4; ++k) {
        int idx = t + k * 256;        // 0..1023
        int n   = idx >> 4;           // 0..63
        int j   = (idx & 15) * 4;     // 0..60
        *(f32x4*)&es[n][j]  = *(const f32x4*)(eb + n * CC + c0 + j);
        *(f32x4*)&is_[n][j] = *(const f32x4*)(ib + n * CC + x0 + j);
    }
    __syncthreads();

    int tx = t & 15, ty = t >> 4;
    float acc[4][4] = {};
    #pragma unroll 8
    for (int n = 0; n < 64; ++n) {
        f32x4 ev = *(const f32x4*)&es[n][ty * 4];
        f32x4 iv = *(const f32x4*)&is_[n][tx * 4];
        #pragma unroll
        for (int i = 0; i < 4; ++i)
            #pragma unroll
            for (int j = 0; j < 4; ++j)
                acc[i][j] += ev[i] * iv[j];
    }

    float* Mb = M + b * CC * CC;
    #pragma unroll
    for (int i = 0; i < 4; ++i) {
        f32x4 v;
        #pragma unroll
        for (int j = 0; j < 4; ++j) v[j] = acc[i][j];
        *(f32x4*)(Mb + (c0 + ty * 4 + i) * CC + x0 + tx * 4) = v;
    }
}

// K34: A-tile = 3x3 stencil of M (on the fly, per 64-wide x-chunk), then
// P[b,n,c] = sum_x img[b,n,x]*A[b,c,x];  out1 = max(P,img)*Spos + min(P,img)*Sneg
__global__ void k34_conv_P_res(const float* __restrict__ M,
                               const float* __restrict__ img,
                               const float* __restrict__ gw,
                               const float* __restrict__ gb,
                               const float* __restrict__ Spos,
                               const float* __restrict__ Sneg,
                               float* __restrict__ out1) {
    __shared__ float Ms[18][68];   // M halo tile: rows c0-1..c0+16, cols x0-1..x0+64
    __shared__ float As[16][68];   // A tile:      rows c0..c0+15,   cols x0..x0+63
    __shared__ float gs[64][68];   // img chunk:   all n,            cols x0..x0+63
    int b  = blockIdx.y;
    int c0 = blockIdx.x * 16;
    int t  = threadIdx.x;
    const float* Mb = M   + b * CC * CC;
    const float* ib = img + b * NN * CC;

    float w[9];
    #pragma unroll
    for (int q = 0; q < 9; ++q) w[q] = gw[q];
    float bias = gb[0];

    int tx = t & 7;   // c-pair 0..7
    int ty = t >> 3;  // n-pair 0..31
    float acc[2][2] = {};

    for (int x0 = 0; x0 < 256; x0 += 64) {
        // stage M halo (zero-padded)
        for (int idx = t; idx < 18 * 66; idx += 256) {
            int r = idx / 66, cl = idx - r * 66;
            int gr = c0 - 1 + r, gc = x0 - 1 + cl;
            float v = 0.0f;
            if (gr >= 0 && gr < 256 && gc >= 0 && gc < 256) v = Mb[gr * 256 + gc];
            Ms[r][cl] = v;
        }
        // stage img chunk
        #pragma unroll
        for (int k = 0; k < 4; ++k) {
            int idx = t + k * 256;
            int n = idx >> 4, j = (idx & 15) * 4;
            *(f32x4*)&gs[n][j] = *(const f32x4*)(ib + n * CC + x0 + j);
        }
        __syncthreads();
        // conv -> A tile
        #pragma unroll
        for (int k = 0; k < 4; ++k) {
            int idx = t + k * 256;
            int ci = idx >> 6, xi = idx & 63;
            float a = bias;
            #pragma unroll
            for (int dc = 0; dc < 3; ++dc)
                #pragma unroll
                for (int dx = 0; dx < 3; ++dx)
                    a += w[dc * 3 + dx] * Ms[ci + dc][xi + dx];
            As[ci][xi] = a;
        }
        __syncthreads();
        // GEMM accumulate over this x-chunk
        #pragma unroll 4
        for (int kk = 0; kk < 16; ++kk) {
            f32x4 g0 = *(const f32x4*)&gs[2 * ty][kk * 4];
            f32x4 g1 = *(const f32x4*)&gs[2 * ty + 1][kk * 4];
            f32x4 a0 = *(const f32x4*)&As[2 * tx][kk * 4];
            f32x4 a1 = *(const f32x4*)&As[2 * tx + 1][kk * 4];
            #pragma unroll
            for (int v = 0; v < 4; ++v) {
                acc[0][0] += g0[v] * a0[v];
                acc[0][1] += g0[v] * a1[v];
                acc[1][0] += g1[v] * a0[v];
                acc[1][1] += g1[v] * a1[v];
            }
        }
        __syncthreads();
    }

    int n0 = 2 * ty;
    float sp0 = Spos[b * NN + n0],     sn0 = Sneg[b * NN + n0];
    float sp1 = Spos[b * NN + n0 + 1], sn1 = Sneg[b * NN + n0 + 1];
    #pragma unroll
    for (int j = 0; j < 2; ++j) {
        int c = c0 + 2 * tx + j;
        float g0 = ib[n0 * CC + c];
        float g1 = ib[(n0 + 1) * CC + c];
        out1[(b * NN + n0) * CC + c]     = fmaxf(acc[0][j], g0) * sp0 + fminf(acc[0][j], g0) * sn0;
        out1[(b * NN + n0 + 1) * CC + c] = fmaxf(acc[1][j], g1) * sp1 + fminf(acc[1][j], g1) * sn1;
    }
}

extern "C" void kernel_launch(void* const* d_in, const int* in_sizes, int n_in,
                              void* d_out, int out_size, void* d_ws, size_t ws_size,
                              hipStream_t stream) {
    const float* img = (const float*)d_in[0];
    const float* tmp = (const float*)d_in[1];
    const float* p1  = (const float*)d_in[2];
    const float* p2  = (const float*)d_in[3];
    const float* w1  = (const float*)d_in[4];
    const float* b1  = (const float*)d_in[5];
    const float* w2  = (const float*)d_in[6];
    const float* b2  = (const float*)d_in[7];
    const float* gw  = (const float*)d_in[8];
    const float* gb  = (const float*)d_in[9];

    float* out0 = (float*)d_out;                 // image_embedding passthrough
    float* out1 = out0 + BB * NN * CC;           // res

    float* ws   = (float*)d_ws;
    float* etpp = ws;                            // B*N*C = 262144
    float* Spos = etpp + BB * NN * CC;           // B*N
    float* Sneg = Spos + BB * NN;                // B*N
    float* M    = Sneg + BB * NN;                // B*C*C = 1048576

    k1_mlp_reduce<<<256, 256, 0, stream>>>(img, tmp, p1, p2, w1, b1, w2, b2,
                                           etpp, Spos, Sneg, out0);
    k2_gemm_M<<<dim3(4, 4, 16), 256, 0, stream>>>(etpp, img, M);
    k34_conv_P_res<<<dim3(16, 16), 256, 0, stream>>>(M, img, gw, gb, Spos, Sneg, out1);
}